// Round 4
// baseline (492.734 us; speedup 1.0000x reference)
//
#include <hip/hip_runtime.h>
#include <hip/hip_bf16.h>
#include <stdint.h>

#define NE   64
#define DIM  1024
#define HID  512
#define TPE  1024   // tokens per expert (uniform in this problem)

typedef __attribute__((ext_vector_type(8)))  __bf16          bf16x8;
typedef __attribute__((ext_vector_type(4)))  float           f32x4;
typedef __attribute__((ext_vector_type(8)))  unsigned short  ushort8_t;
typedef __attribute__((ext_vector_type(4)))  float           float4_t;

__device__ __forceinline__ unsigned short f2bf(float f) {
  return __builtin_bit_cast(unsigned short, static_cast<__bf16>(f));  // RNE
}
__device__ __forceinline__ float bf2f(unsigned short u) {
  unsigned int x = ((unsigned int)u) << 16;
  return __builtin_bit_cast(float, x);
}
__device__ __forceinline__ ushort8_t pack8(float4_t a, float4_t b) {
  ushort8_t r;
  r[0] = f2bf(a[0]); r[1] = f2bf(a[1]); r[2] = f2bf(a[2]); r[3] = f2bf(a[3]);
  r[4] = f2bf(b[0]); r[5] = f2bf(b[1]); r[6] = f2bf(b[2]); r[7] = f2bf(b[3]);
  return r;
}
__device__ __forceinline__ bf16x8 ldsfrag(const unsigned short* p) {
  return __builtin_bit_cast(bf16x8, *reinterpret_cast<const ushort8_t*>(p));
}

// LDS row stride 40 bf16 (80 B): 16B-granule g = 5*row + k16; over any frag
// read (row = base+fr, fr=lane&15, k16=lane>>4) each of the 8 bank-groups is
// hit exactly 8x per wave64 -> uniform, conflict-free schedule.
#define LDK 40

// XCD-aware bijective swizzle (grid % 8 == 0): contiguous chunk per XCD.
__device__ __forceinline__ int xcd_swizzle(int bid, int nwg) {
  return (bid & 7) * (nwg >> 3) + (bid >> 3);
}

// ---------------------------------------------------------------------------
// Phase 1: H = bf16( silu(X@W1^T) * (X@W3^T) ), per expert.
// m97-shape: BM=128 x BN=64, BK=32, 256 thr = 4 waves (2Mx2N), wave 64x32 dual.
// Per wave-Kstep: 8 ds_read_b128 -> 16 MFMA (ratio 2.0 with dual acc).
// LDS 40 KB dbuf; __launch_bounds__(256,3) -> ~3 blocks/CU co-resident so
// other blocks' MFMAs cover this block's barrier/vmcnt drain (m97 mechanism).
// ---------------------------------------------------------------------------
#define P1_NKT (DIM / 32)

__global__ __launch_bounds__(256, 3) void p1_kernel(
    const float* __restrict__ X, const float* __restrict__ W1,
    const float* __restrict__ W3, unsigned short* __restrict__ H) {
  __shared__ __align__(16) unsigned short lA [2][128 * LDK];  // 20480 B
  __shared__ __align__(16) unsigned short lB1[2][ 64 * LDK];  // 10240 B
  __shared__ __align__(16) unsigned short lB3[2][ 64 * LDK];  // 10240 B

  const int tile = xcd_swizzle(blockIdx.x, NE * 8 * 8);
  const int e  = tile >> 6;
  const int tm = (tile >> 3) & 7;    // 8 token tiles of 128
  const int tn = tile & 7;           // 8 hid tiles of 64 (inner: X slab L2-hot)
  const int t  = threadIdx.x;

  const float* gA  = X  + (size_t)(e * TPE + tm * 128) * DIM;
  const float* gB1 = W1 + ((size_t)e * HID + tn * 64) * DIM;
  const float* gB3 = W3 + ((size_t)e * HID + tn * 64) * DIM;

  // A: 128x32 fl / 256 thr = 16 fl: row t>>1, cols (t&1)*16.. (64 B contig)
  // B: 64x32 fl / 256 thr = 8 fl:  row t>>2, cols (t&3)*8   (32 B contig)
  const int arow = t >> 1, acol = (t & 1) * 16;
  const int brow = t >> 2, bcol = (t & 3) * 8;

  float4_t ra[4], rb1[2], rb3[2];

  auto load_g = [&](int kt) {
    const size_t ao = (size_t)arow * DIM + kt * 32 + acol;
#pragma unroll
    for (int i = 0; i < 4; ++i)
      ra[i] = *reinterpret_cast<const float4_t*>(gA + ao + 4 * i);
    const size_t bo = (size_t)brow * DIM + kt * 32 + bcol;
    rb1[0] = *reinterpret_cast<const float4_t*>(gB1 + bo);
    rb1[1] = *reinterpret_cast<const float4_t*>(gB1 + bo + 4);
    rb3[0] = *reinterpret_cast<const float4_t*>(gB3 + bo);
    rb3[1] = *reinterpret_cast<const float4_t*>(gB3 + bo + 4);
  };
  auto store_l = [&](int buf) {
    const int ai = arow * LDK + acol;
    *reinterpret_cast<ushort8_t*>(&lA[buf][ai])     = pack8(ra[0], ra[1]);
    *reinterpret_cast<ushort8_t*>(&lA[buf][ai + 8]) = pack8(ra[2], ra[3]);
    *reinterpret_cast<ushort8_t*>(&lB1[buf][brow * LDK + bcol]) = pack8(rb1[0], rb1[1]);
    *reinterpret_cast<ushort8_t*>(&lB3[buf][brow * LDK + bcol]) = pack8(rb3[0], rb3[1]);
  };

  const int lane = t & 63;
  const int wv   = t >> 6;
  const int wr   = wv >> 1, wc = wv & 1;   // 2x2 waves: 64M x 32N each
  const int fr   = lane & 15;
  const int ks   = (lane >> 4) * 8;

  f32x4 acc1[4][2], acc3[4][2];
#pragma unroll
  for (int mi = 0; mi < 4; ++mi)
#pragma unroll
    for (int ni = 0; ni < 2; ++ni)
#pragma unroll
      for (int i = 0; i < 4; ++i) { acc1[mi][ni][i] = 0.f; acc3[mi][ni][i] = 0.f; }

  auto mfma_phase = [&](int buf) {
    bf16x8 b1f[2], b3f[2], af[4];
#pragma unroll
    for (int ni = 0; ni < 2; ++ni) {
      const int bi = (wc * 32 + ni * 16 + fr) * LDK + ks;
      b1f[ni] = ldsfrag(&lB1[buf][bi]);
      b3f[ni] = ldsfrag(&lB3[buf][bi]);
    }
#pragma unroll
    for (int mi = 0; mi < 4; ++mi)
      af[mi] = ldsfrag(&lA[buf][(wr * 64 + mi * 16 + fr) * LDK + ks]);
#pragma unroll
    for (int mi = 0; mi < 4; ++mi)
#pragma unroll
      for (int ni = 0; ni < 2; ++ni) {
        acc1[mi][ni] = __builtin_amdgcn_mfma_f32_16x16x32_bf16(af[mi], b1f[ni], acc1[mi][ni], 0, 0, 0);
        acc3[mi][ni] = __builtin_amdgcn_mfma_f32_16x16x32_bf16(af[mi], b3f[ni], acc3[mi][ni], 0, 0, 0);
      }
  };

  load_g(0);
  for (int kt = 0; kt < P1_NKT; ++kt) {
    const int buf = kt & 1;
    store_l(buf);                         // waits (reg-dep) on current loads
    __syncthreads();
    if (kt + 1 < P1_NKT) load_g(kt + 1);  // overlaps MFMA; drain covered by
    mfma_phase(buf);                      // co-resident blocks (3/CU)
  }

  // epilogue: silu(a)*b. 16x16 C/D: col=lane&15, row=(lane>>4)*4+reg [m89]
  const int tokBase = e * TPE + tm * 128 + wr * 64;
  const int hidBase = tn * 64 + wc * 32;
#pragma unroll
  for (int mi = 0; mi < 4; ++mi)
#pragma unroll
    for (int ni = 0; ni < 2; ++ni)
#pragma unroll
      for (int r = 0; r < 4; ++r) {
        const int tok = tokBase + mi * 16 + (lane >> 4) * 4 + r;
        const int hid = hidBase + ni * 16 + fr;
        const float av = bf2f(f2bf(acc1[mi][ni][r]));  // ref bf16 rounding
        const float bv = bf2f(f2bf(acc3[mi][ni][r]));
        const float s  = av / (1.0f + __expf(-av));
        H[(size_t)tok * HID + hid] = f2bf(s * bv);
      }
}

// ---------------------------------------------------------------------------
// Phase 2: OUT = fp32( bf16( H @ W2^T ) ), per expert.
// BM=128 x BN=128, BK=32, 256 thr = 4 waves (2x2), wave 64x64 single acc.
// Per wave-Kstep: 8 ds_read_b128 -> 16 MFMA (ratio 2.0). LDS 40 KB dbuf.
// ---------------------------------------------------------------------------
#define P2_NKT (HID / 32)

__global__ __launch_bounds__(256, 3) void p2_kernel(
    const unsigned short* __restrict__ Hin, const float* __restrict__ W2,
    float* __restrict__ OUT) {
  __shared__ __align__(16) unsigned short lA[2][128 * LDK];  // 20480 B
  __shared__ __align__(16) unsigned short lB[2][128 * LDK];  // 20480 B

  const int tile = xcd_swizzle(blockIdx.x, NE * 8 * 8);
  const int e  = tile >> 6;
  const int tm = (tile >> 3) & 7;    // 8 token tiles of 128
  const int tn = tile & 7;           // 8 dim tiles of 128
  const int t  = threadIdx.x;

  const unsigned short* gA = Hin + (size_t)(e * TPE + tm * 128) * HID;
  const float*          gB = W2  + ((size_t)e * DIM + tn * 128) * HID;

  // A (bf16): 128x32 sh / 256 thr = 16 sh: row t>>1, cols (t&1)*16 (32 B)
  // B (fp32): 128x32 fl / 256 thr = 16 fl: row t>>1, cols (t&1)*16 (64 B)
  const int arow = t >> 1, acol = (t & 1) * 16;

  ushort8_t ra[2];
  float4_t  rb[4];

  auto load_g = [&](int kt) {
    const size_t ao = (size_t)arow * HID + kt * 32 + acol;
    ra[0] = *reinterpret_cast<const ushort8_t*>(gA + ao);
    ra[1] = *reinterpret_cast<const ushort8_t*>(gA + ao + 8);
    const size_t bo = (size_t)arow * HID + kt * 32 + acol;
#pragma unroll
    for (int i = 0; i < 4; ++i)
      rb[i] = *reinterpret_cast<const float4_t*>(gB + bo + 4 * i);
  };
  auto store_l = [&](int buf) {
    const int ai = arow * LDK + acol;
    *reinterpret_cast<ushort8_t*>(&lA[buf][ai])     = ra[0];
    *reinterpret_cast<ushort8_t*>(&lA[buf][ai + 8]) = ra[1];
    *reinterpret_cast<ushort8_t*>(&lB[buf][ai])     = pack8(rb[0], rb[1]);
    *reinterpret_cast<ushort8_t*>(&lB[buf][ai + 8]) = pack8(rb[2], rb[3]);
  };

  const int lane = t & 63;
  const int wv   = t >> 6;
  const int wr   = wv >> 1, wc = wv & 1;   // 2x2 waves, 64x64 each
  const int fr   = lane & 15;
  const int ks   = (lane >> 4) * 8;

  f32x4 acc[4][4];
#pragma unroll
  for (int mi = 0; mi < 4; ++mi)
#pragma unroll
    for (int ni = 0; ni < 4; ++ni)
#pragma unroll
      for (int i = 0; i < 4; ++i) acc[mi][ni][i] = 0.f;

  auto mfma_phase = [&](int buf) {
    bf16x8 bfr[4], af[4];
#pragma unroll
    for (int ni = 0; ni < 4; ++ni)
      bfr[ni] = ldsfrag(&lB[buf][(wc * 64 + ni * 16 + fr) * LDK + ks]);
#pragma unroll
    for (int mi = 0; mi < 4; ++mi)
      af[mi] = ldsfrag(&lA[buf][(wr * 64 + mi * 16 + fr) * LDK + ks]);
#pragma unroll
    for (int mi = 0; mi < 4; ++mi)
#pragma unroll
      for (int ni = 0; ni < 4; ++ni)
        acc[mi][ni] = __builtin_amdgcn_mfma_f32_16x16x32_bf16(af[mi], bfr[ni], acc[mi][ni], 0, 0, 0);
  };

  load_g(0);
  for (int kt = 0; kt < P2_NKT; ++kt) {
    const int buf = kt & 1;
    store_l(buf);
    __syncthreads();
    if (kt + 1 < P2_NKT) load_g(kt + 1);
    mfma_phase(buf);
  }

  const int tokBase = e * TPE + tm * 128 + wr * 64;
  const int dBase   = tn * 128 + wc * 64;
#pragma unroll
  for (int mi = 0; mi < 4; ++mi)
#pragma unroll
    for (int ni = 0; ni < 4; ++ni)
#pragma unroll
      for (int r = 0; r < 4; ++r) {
        const int tok = tokBase + mi * 16 + (lane >> 4) * 4 + r;
        const int d   = dBase + ni * 16 + fr;
        OUT[(size_t)tok * DIM + d] = bf2f(f2bf(acc[mi][ni][r]));  // ref bf16->f32
      }
}

// ---------------------------------------------------------------------------
extern "C" void kernel_launch(void* const* d_in, const int* in_sizes, int n_in,
                              void* d_out, int out_size, void* d_ws, size_t ws_size,
                              hipStream_t stream) {
  (void)in_sizes; (void)n_in; (void)out_size; (void)ws_size;
  const float* X  = (const float*)d_in[0];
  const float* W1 = (const float*)d_in[1];
  const float* W2 = (const float*)d_in[2];
  const float* W3 = (const float*)d_in[3];
  // d_in[4] = num_tokens_per_expert: uniform 1024/expert in this problem.

  unsigned short* H = (unsigned short*)d_ws;   // 65536 x 512 bf16 = 64 MiB
  float* OUT = (float*)d_out;

  p1_kernel<<<dim3(NE * 8 * 8), dim3(256), 0, stream>>>(X, W1, W3, H);
  p2_kernel<<<dim3(NE * 8 * 8), dim3(256), 0, stream>>>(H, W2, OUT);
}